// Round 4
// baseline (90.965 us; speedup 1.0000x reference)
//
#include <hip/hip_runtime.h>
#include <hip/hip_bf16.h>

#define DI __device__ __forceinline__

typedef __bf16 bf16x8 __attribute__((ext_vector_type(8)));
typedef float f32x16 __attribute__((ext_vector_type(16)));

typedef const void __attribute__((address_space(1))) gas_t;
typedef void __attribute__((address_space(3))) las_t;

DI unsigned short f2bf(float f) {
    unsigned u = __builtin_bit_cast(unsigned, f);
    u += 0x7fffu + ((u >> 16) & 1u);   // RNE
    return (unsigned short)(u >> 16);
}

// ---------------- prep: GN stats (512 blocks) + weight cvt (1024 blocks) ----
__global__ __launch_bounds__(256) void prep_kernel(const float* __restrict__ x,
                                                   float2* __restrict__ part,
                                                   const float* __restrict__ w0,
                                                   const float* __restrict__ w1,
                                                   const float* __restrict__ w2,
                                                   const float* __restrict__ w3,
                                                   unsigned short* __restrict__ wb) {
    int bx = blockIdx.x;
    int t = threadIdx.x;
    if (bx < 512) {
        // stats: block = (b,g,ch): 8 channels x 1024 px
        size_t base = (size_t)bx * 8 * 1024;
        const float4* xp = (const float4*)(x + base);
        float s = 0.f, q = 0.f;
#pragma unroll
        for (int it = 0; it < 8; ++it) {
            float4 v = xp[it * 256 + t];
            s += (v.x + v.y) + (v.z + v.w);
            q += (v.x * v.x + v.y * v.y) + (v.z * v.z + v.w * v.w);
        }
#pragma unroll
        for (int o = 32; o; o >>= 1) { s += __shfl_xor(s, o); q += __shfl_xor(q, o); }
        __shared__ float rs[4], rq[4];
        int lane = t & 63, wid = t >> 6;
        if (!lane) { rs[wid] = s; rq[wid] = q; }
        __syncthreads();
        if (t == 0)
            part[bx] = make_float2(rs[0] + rs[1] + rs[2] + rs[3],
                                   rq[0] + rq[1] + rq[2] + rq[3]);
    } else {
        int idx4 = bx - 512;                 // 0..1023
        int w = idx4 >> 8;
        const float* s = (w == 0) ? w0 : (w == 1) ? w1 : (w == 2) ? w2 : w3;
        unsigned short* o = wb + (size_t)w * 262144;
        int idx = (idx4 & 255) * 256 + t;
        float4 v = ((const float4*)s)[idx];
        ushort4 r;
        r.x = f2bf(v.x); r.y = f2bf(v.y); r.z = f2bf(v.z); r.w = f2bf(v.w);
        ((ushort4*)o)[idx] = r;
    }
}

// -------- GN apply + transposed write: x[b,c,hw] f32 -> hT[b,hw,c] bf16 -----
__global__ __launch_bounds__(256) void gn_applyT(const float* __restrict__ x,
                                                 const float2* __restrict__ part,
                                                 const float* __restrict__ gs,
                                                 const float* __restrict__ gb,
                                                 unsigned short* __restrict__ hT) {
    int bg = blockIdx.x >> 3, ic = blockIdx.x & 7;
    int b = bg >> 3, g = bg & 7;
    float s = 0.f, q = 0.f;
#pragma unroll
    for (int k = 0; k < 8; ++k) { float2 p = part[bg * 8 + k]; s += p.x; q += p.y; }
    float mean = s * (1.f / 65536.f);
    float var = q * (1.f / 65536.f) - mean * mean;
    float rstd = rsqrtf(var + 1e-5f);

    __shared__ unsigned short tile[128 * 66];   // [i][c], stride 66
    int t = threadIdx.x;
    int i4 = t & 31, cq = t >> 5;
    size_t xbase = ((size_t)b * 512 + g * 64) * 1024 + ic * 128;
#pragma unroll
    for (int pass = 0; pass < 8; ++pass) {
        int c = pass * 8 + cq;
        float4 v = *(const float4*)&x[xbase + (size_t)c * 1024 + i4 * 4];
        int gc = g * 64 + c;
        float sc = gs[gc] * rstd, bi = gb[gc] - mean * sc;
        unsigned short* tp = &tile[(i4 * 4) * 66 + c];
        tp[0]   = f2bf(v.x * sc + bi);
        tp[66]  = f2bf(v.y * sc + bi);
        tp[132] = f2bf(v.z * sc + bi);
        tp[198] = f2bf(v.w * sc + bi);
    }
    __syncthreads();
    int i = t >> 1, h = t & 1;
    const unsigned short* tp2 = &tile[i * 66 + h * 32];
    unsigned short* op = &hT[(size_t)b * (1024 * 512) + (size_t)(ic * 128 + i) * 512 + g * 64 + h * 32];
#pragma unroll
    for (int cc = 0; cc < 4; ++cc) {
        unsigned short tmp[8];
#pragma unroll
        for (int j = 0; j < 8; ++j) tmp[j] = tp2[cc * 8 + j];
        *(uint4*)&op[cc * 8] = *(const uint4*)tmp;
    }
}

// ------- staging: global tile (ROWS x 64 k bf16) -> LDS via LDS-DMA ---------
// LDS: linear rows of 128B; slot s of row r holds global k-slot s^(r&7).
template <int ROWS>
DI void stage_tile(const unsigned short* __restrict__ g, int ldK,
                   unsigned short* lds, int t) {
    int row_in = t >> 3;                        // 0..31
    int kg = (t & 7) ^ (row_in & 7);            // pre-swizzled global slot
    const unsigned short* src = g + (size_t)row_in * ldK + kg * 8;
    unsigned short* dst = lds + ((t >> 6) << 9);  // wave-uniform base
#pragma unroll
    for (int c = 0; c < ROWS / 32; ++c) {
        __builtin_amdgcn_global_load_lds(
            (gas_t*)(unsigned long long)(src + (size_t)c * 32 * ldK),
            (las_t*)(unsigned)(unsigned long long)(dst + c * 2048),
            16, 0, 0);
    }
}

DI bf16x8 frag(const unsigned short* lds, int r, int kg) {
    return *(const bf16x8*)((const char*)lds + r * 128 + ((kg ^ (r & 7)) << 4));
}

// ------------- GEMM engine: C[M,N] = A[M,K] * B[N,K]^T, tile TM x 128 -------
// 32x32x16 MFMA. Wave = (TM/2) x 64 output. C/D: col=lane&31,
// row=(reg&3)+8*(reg>>2)+4*(lane>>5)  [m74/m101 verified]
// MODE 0: QKV fused (TM=128): m0<512 -> qT C^T(+b0); <1024 -> kT(+b1); else vN nat(+b2)
// MODE 1: scores -> E = exp(acc*scale) bf16 C^T + partial row sums to spart
// MODE 2: PV -> bf16 C^T, scaled by 1/rowsum (from spart)
// MODE 3: proj -> f32 C^T + bias[ng] + residual
template <int TM, int MODE, int MINW>
__global__ __launch_bounds__(256, MINW) void gemm_bt(
        const unsigned short* __restrict__ A, const unsigned short* __restrict__ B,
        const float* __restrict__ b0, const float* __restrict__ b1,
        const float* __restrict__ b2,
        void* __restrict__ C0, void* __restrict__ C1, void* __restrict__ C2,
        const float* __restrict__ resid, float* __restrict__ spart,
        int M, int N, int K, float scale, size_t sA, size_t sB, size_t sC) {
    constexpr int MB = TM / 64;                       // 32-row m-blocks per wave
    __shared__ __align__(16) unsigned short As[TM * 64];
    __shared__ __align__(16) unsigned short Bs[128 * 64];
    int bx = blockIdx.x;
    int b = bx & 7;                 // batch fastest -> XCD-resident per batch
    int tile = bx >> 3;
    int nTx = N >> 7;
    int tx = tile % nTx, ty = tile / nTx;
    int m0 = ty * TM, n0 = tx << 7;
    const unsigned short* Ag = A + sA * b + (size_t)m0 * K;
    const unsigned short* Bg = B + sB * b + (size_t)n0 * K;
    int t = threadIdx.x;
    int lane = t & 63, wid = t >> 6;
    int wm = (wid >> 1) * (TM / 2), wn = (wid & 1) * 64;
    const int l31 = lane & 31, lhi = lane >> 5;

    f32x16 acc[MB][2];
#pragma unroll
    for (int i = 0; i < MB; ++i)
#pragma unroll
        for (int j = 0; j < 2; ++j) acc[i][j] = (f32x16)(0.f);

    for (int k0 = 0; k0 < K; k0 += 64) {
        stage_tile<TM>(Ag + k0, K, As, t);
        stage_tile<128>(Bg + k0, K, Bs, t);
        asm volatile("s_waitcnt vmcnt(0)" ::: "memory");
        __syncthreads();
#pragma unroll
        for (int kk = 0; kk < 4; ++kk) {
            int slot = kk * 2 + lhi;
            bf16x8 a_[MB], b_[2];
#pragma unroll
            for (int m = 0; m < MB; ++m) a_[m] = frag(As, wm + m * 32 + l31, slot);
#pragma unroll
            for (int n = 0; n < 2; ++n) b_[n] = frag(Bs, wn + n * 32 + l31, slot);
#pragma unroll
            for (int m = 0; m < MB; ++m)
#pragma unroll
                for (int n = 0; n < 2; ++n)
                    acc[m][n] = __builtin_amdgcn_mfma_f32_32x32x16_bf16(a_[m], b_[n], acc[m][n], 0, 0, 0);
        }
        __syncthreads();
    }

    const size_t cb = sC * b;
    const int r4 = 4 * lhi;
    if constexpr (MODE == 0) {
        if (m0 < 1024) {
            unsigned short* Ct = (unsigned short*)(m0 < 512 ? C0 : C1) + cb;
            const float* bias = (m0 < 512) ? b0 : b1;
            int moff = (m0 < 512) ? 0 : 512;
#pragma unroll
            for (int m = 0; m < MB; ++m) {
#pragma unroll
                for (int q = 0; q < 4; ++q) {
                    int mg = m0 - moff + wm + m * 32 + q * 8 + r4;
                    float bv4[4];
#pragma unroll
                    for (int j = 0; j < 4; ++j) bv4[j] = bias[mg + j];
#pragma unroll
                    for (int n = 0; n < 2; ++n) {
                        int ng = n0 + wn + n * 32 + l31;
                        f32x16 v = acc[m][n];
                        ushort4 o;
                        o.x = f2bf(v[4 * q + 0] + bv4[0]);
                        o.y = f2bf(v[4 * q + 1] + bv4[1]);
                        o.z = f2bf(v[4 * q + 2] + bv4[2]);
                        o.w = f2bf(v[4 * q + 3] + bv4[3]);
                        *(ushort4*)&Ct[(size_t)ng * 512 + mg] = o;
                    }
                }
            }
        } else {
            unsigned short* Vb = (unsigned short*)C2 + cb;
#pragma unroll
            for (int m = 0; m < MB; ++m) {
#pragma unroll
                for (int q = 0; q < 4; ++q) {
                    int mg = m0 - 1024 + wm + m * 32 + q * 8 + r4;
                    float bv4[4];
#pragma unroll
                    for (int j = 0; j < 4; ++j) bv4[j] = b2[mg + j];
#pragma unroll
                    for (int n = 0; n < 2; ++n) {
                        int ng = n0 + wn + n * 32 + l31;
                        f32x16 v = acc[m][n];
#pragma unroll
                        for (int j = 0; j < 4; ++j)
                            Vb[(size_t)(mg + j) * 1024 + ng] = f2bf(v[4 * q + j] + bv4[j]);
                    }
                }
            }
        }
    } else if constexpr (MODE == 1) {
        unsigned short* Ct = (unsigned short*)C0 + cb;
        float psum[2] = {0.f, 0.f};
#pragma unroll
        for (int m = 0; m < MB; ++m) {
#pragma unroll
            for (int q = 0; q < 4; ++q) {
                int mg = m0 + wm + m * 32 + q * 8 + r4;
#pragma unroll
                for (int n = 0; n < 2; ++n) {
                    int ng = n0 + wn + n * 32 + l31;
                    f32x16 v = acc[m][n];
                    float e0 = __expf(v[4 * q + 0] * scale);
                    float e1 = __expf(v[4 * q + 1] * scale);
                    float e2 = __expf(v[4 * q + 2] * scale);
                    float e3 = __expf(v[4 * q + 3] * scale);
                    psum[n] += (e0 + e1) + (e2 + e3);
                    ushort4 o;
                    o.x = f2bf(e0); o.y = f2bf(e1); o.z = f2bf(e2); o.w = f2bf(e3);
                    *(ushort4*)&Ct[(size_t)ng * M + mg] = o;
                }
            }
        }
        int rb = (m0 >> 7) * 2 + (wid >> 1);
#pragma unroll
        for (int n = 0; n < 2; ++n) {
            float p = psum[n];
            p += __shfl_xor(p, 32);
            if (lane < 32) {
                int ng = n0 + wn + n * 32 + l31;
                spart[(size_t)(b * 16 + rb) * 1024 + ng] = p;
            }
        }
    } else if constexpr (MODE == 2) {
        unsigned short* Ct = (unsigned short*)C0 + cb;
        float inv[2];
#pragma unroll
        for (int n = 0; n < 2; ++n) {
            int ng = n0 + wn + n * 32 + l31;
            float ssum = 0.f;
#pragma unroll
            for (int k = 0; k < 16; ++k) ssum += spart[(size_t)(b * 16 + k) * 1024 + ng];
            inv[n] = 1.f / ssum;
        }
#pragma unroll
        for (int m = 0; m < MB; ++m) {
#pragma unroll
            for (int q = 0; q < 4; ++q) {
                int mg = m0 + wm + m * 32 + q * 8 + r4;
#pragma unroll
                for (int n = 0; n < 2; ++n) {
                    int ng = n0 + wn + n * 32 + l31;
                    f32x16 v = acc[m][n];
                    ushort4 o;
                    o.x = f2bf(v[4 * q + 0] * inv[n]);
                    o.y = f2bf(v[4 * q + 1] * inv[n]);
                    o.z = f2bf(v[4 * q + 2] * inv[n]);
                    o.w = f2bf(v[4 * q + 3] * inv[n]);
                    *(ushort4*)&Ct[(size_t)ng * M + mg] = o;
                }
            }
        }
    } else {
        float* Cf = (float*)C0 + cb;
#pragma unroll
        for (int m = 0; m < MB; ++m) {
#pragma unroll
            for (int q = 0; q < 4; ++q) {
                int mg = m0 + wm + m * 32 + q * 8 + r4;
#pragma unroll
                for (int n = 0; n < 2; ++n) {
                    int ng = n0 + wn + n * 32 + l31;
                    float bn = b0[ng];
                    f32x16 v = acc[m][n];
                    const float* rp = resid + cb + (size_t)ng * M + mg;
                    float4 o;
                    o.x = v[4 * q + 0] + bn + rp[0];
                    o.y = v[4 * q + 1] + bn + rp[1];
                    o.z = v[4 * q + 2] + bn + rp[2];
                    o.w = v[4 * q + 3] + bn + rp[3];
                    *(float4*)&Cf[(size_t)ng * M + mg] = o;
                }
            }
        }
    }
}

extern "C" void kernel_launch(void* const* d_in, const int* in_sizes, int n_in,
                              void* d_out, int out_size, void* d_ws, size_t ws_size,
                              hipStream_t stream) {
    const float* x  = (const float*)d_in[0];
    const float* gs = (const float*)d_in[1];
    const float* gb = (const float*)d_in[2];
    const float* wq = (const float*)d_in[3];
    const float* bq = (const float*)d_in[4];
    const float* wk = (const float*)d_in[5];
    const float* bk = (const float*)d_in[6];
    const float* wv = (const float*)d_in[7];
    const float* bv = (const float*)d_in[8];
    const float* wp = (const float*)d_in[9];
    const float* bp = (const float*)d_in[10];
    float* out = (float*)d_out;

    char* ws = (char*)d_ws;
    const size_t MB_ = 1u << 20;
    unsigned short* hT = (unsigned short*)(ws + 0);         // [b][1024][512]
    unsigned short* wb = (unsigned short*)(ws + 8 * MB_);   // [wq;wk;wv;wp] bf16
    unsigned short* qT = (unsigned short*)(ws + 10 * MB_);  // [b][1024][512]
    unsigned short* kT = (unsigned short*)(ws + 18 * MB_);  // [b][1024][512]
    unsigned short* vN = (unsigned short*)(ws + 26 * MB_);  // [b][512][1024]
    unsigned short* E  = (unsigned short*)(ws + 34 * MB_);  // [b][1024][1024] bf16
    unsigned short* OT = (unsigned short*)(ws + 50 * MB_);  // [b][1024][512]
    float2* gnpart     = (float2*)(ws + 58 * MB_);          // 512 x float2
    float*  spart      = (float*)(ws + 58 * MB_ + 65536);   // [b][16][1024] f32

    const unsigned short* wpb = wb + 3 * 262144;
    const size_t sH = 1024 * 512;
    const size_t sS = 1024 * 1024;

    prep_kernel<<<1536, 256, 0, stream>>>(x, gnpart, wq, wk, wv, wp, wb);
    gn_applyT<<<512, 256, 0, stream>>>(x, gnpart, gs, gb, hT);

    // QKV fused: A = [Wq;Wk;Wv] (1536x512), B = hT -> qT, kT (C^T), vN (nat)
    gemm_bt<128, 0, 3><<<96 * 8, 256, 0, stream>>>(
        wb, hT, bq, bk, bv, qT, kT, vN, nullptr, nullptr,
        1536, 1024, 512, 1.f, 0, sH, sH);
    // scores: A=kT, B=qT -> E[i][j] = exp(s*scale) bf16 (C^T) + spart
    gemm_bt<128, 1, 3><<<64 * 8, 256, 0, stream>>>(
        kT, qT, nullptr, nullptr, nullptr, E, nullptr, nullptr, nullptr, spart,
        1024, 1024, 512, 0.044194173824159216f, sH, sH, sS);
    // PV: A=vN, B=E -> OT[i][c] (C^T), normalized by rowsum
    gemm_bt<64, 2, 3><<<64 * 8, 256, 0, stream>>>(
        vN, E, nullptr, nullptr, nullptr, OT, nullptr, nullptr, nullptr, spart,
        512, 1024, 1024, 1.f, sH, sS, sH);
    // proj: A=OT, B=Wp -> out[b][c][i] f32 (C^T) + bias[c] + residual
    gemm_bt<64, 3, 3><<<64 * 8, 256, 0, stream>>>(
        OT, wpb, bp, nullptr, nullptr, out, nullptr, nullptr, x, nullptr,
        1024, 512, 512, 1.f, sH, 0, (size_t)512 * 1024);
}

// Round 5
// 80.384 us; speedup vs baseline: 1.1316x; 1.1316x over previous
//
#include <hip/hip_runtime.h>
#include <hip/hip_bf16.h>

#define DI __device__ __forceinline__

typedef __bf16 bf16x8 __attribute__((ext_vector_type(8)));
typedef float f32x4 __attribute__((ext_vector_type(4)));

typedef const void __attribute__((address_space(1))) gas_t;
typedef void __attribute__((address_space(3))) las_t;

DI unsigned short f2bf(float f) {
    unsigned u = __builtin_bit_cast(unsigned, f);
    u += 0x7fffu + ((u >> 16) & 1u);   // RNE
    return (unsigned short)(u >> 16);
}

// ---------------- prep: GN stats (512 blocks) + weight cvt (1024 blocks) ----
// stats blocks: batch = bx&7 so x[b] warms XCD-b L2 (consumed by gn_applyT)
__global__ __launch_bounds__(256) void prep_kernel(const float* __restrict__ x,
                                                   float2* __restrict__ part,
                                                   const float* __restrict__ w0,
                                                   const float* __restrict__ w1,
                                                   const float* __restrict__ w2,
                                                   const float* __restrict__ w3,
                                                   unsigned short* __restrict__ wb) {
    int bx = blockIdx.x;
    int t = threadIdx.x;
    if (bx < 512) {
        // unit = (b,g,ch): 8 channels x 1024 px. batch in low 3 bits -> XCD
        int b = bx & 7, g = (bx >> 3) & 7, ch = bx >> 6;
        size_t base = ((size_t)b * 512 + g * 64 + ch * 8) * 1024;
        const float4* xp = (const float4*)(x + base);
        float s = 0.f, q = 0.f;
#pragma unroll
        for (int it = 0; it < 8; ++it) {
            float4 v = xp[it * 256 + t];
            s += (v.x + v.y) + (v.z + v.w);
            q += (v.x * v.x + v.y * v.y) + (v.z * v.z + v.w * v.w);
        }
#pragma unroll
        for (int o = 32; o; o >>= 1) { s += __shfl_xor(s, o); q += __shfl_xor(q, o); }
        __shared__ float rs[4], rq[4];
        int lane = t & 63, wid = t >> 6;
        if (!lane) { rs[wid] = s; rq[wid] = q; }
        __syncthreads();
        if (t == 0)
            part[((b * 8 + g) * 8) + ch] =
                make_float2(rs[0] + rs[1] + rs[2] + rs[3],
                            rq[0] + rq[1] + rq[2] + rq[3]);
    } else {
        int idx4 = bx - 512;                 // 0..1023
        int w = idx4 >> 8;
        const float* s = (w == 0) ? w0 : (w == 1) ? w1 : (w == 2) ? w2 : w3;
        unsigned short* o = wb + (size_t)w * 262144;
        int idx = (idx4 & 255) * 256 + t;
        float4 v = ((const float4*)s)[idx];
        ushort4 r;
        r.x = f2bf(v.x); r.y = f2bf(v.y); r.z = f2bf(v.z); r.w = f2bf(v.w);
        ((ushort4*)o)[idx] = r;
    }
}

// -------- GN apply + transposed write: x[b,c,hw] f32 -> hT[b,hw,c] bf16 -----
// batch = bx&7: reads x[b] from XCD-b L2 (warmed by prep), writes hT[b] into
// XCD-b L2 (consumed by QKV blocks with b = bx&7).
__global__ __launch_bounds__(256) void gn_applyT(const float* __restrict__ x,
                                                 const float2* __restrict__ part,
                                                 const float* __restrict__ gs,
                                                 const float* __restrict__ gb,
                                                 unsigned short* __restrict__ hT) {
    int bx = blockIdx.x;
    int b = bx & 7, g = (bx >> 3) & 7, ic = bx >> 6;
    int bg = b * 8 + g;
    float s = 0.f, q = 0.f;
#pragma unroll
    for (int k = 0; k < 8; ++k) { float2 p = part[bg * 8 + k]; s += p.x; q += p.y; }
    float mean = s * (1.f / 65536.f);
    float var = q * (1.f / 65536.f) - mean * mean;
    float rstd = rsqrtf(var + 1e-5f);

    __shared__ unsigned short tile[128 * 66];   // [i][c], stride 66
    int t = threadIdx.x;
    int i4 = t & 31, cq = t >> 5;
    size_t xbase = ((size_t)b * 512 + g * 64) * 1024 + ic * 128;
#pragma unroll
    for (int pass = 0; pass < 8; ++pass) {
        int c = pass * 8 + cq;
        float4 v = *(const float4*)&x[xbase + (size_t)c * 1024 + i4 * 4];
        int gc = g * 64 + c;
        float sc = gs[gc] * rstd, bi = gb[gc] - mean * sc;
        unsigned short* tp = &tile[(i4 * 4) * 66 + c];
        tp[0]   = f2bf(v.x * sc + bi);
        tp[66]  = f2bf(v.y * sc + bi);
        tp[132] = f2bf(v.z * sc + bi);
        tp[198] = f2bf(v.w * sc + bi);
    }
    __syncthreads();
    int i = t >> 1, h = t & 1;
    const unsigned short* tp2 = &tile[i * 66 + h * 32];
    unsigned short* op = &hT[(size_t)b * (1024 * 512) + (size_t)(ic * 128 + i) * 512 + g * 64 + h * 32];
#pragma unroll
    for (int cc = 0; cc < 4; ++cc) {
        unsigned short tmp[8];
#pragma unroll
        for (int j = 0; j < 8; ++j) tmp[j] = tp2[cc * 8 + j];
        *(uint4*)&op[cc * 8] = *(const uint4*)tmp;
    }
}

// ------- staging: global tile (ROWS x 64 k bf16) -> LDS via LDS-DMA ---------
// LDS: linear rows of 128B; slot s of row r holds global k-slot s^(r&7).
template <int ROWS>
DI void stage_tile(const unsigned short* __restrict__ g, int ldK,
                   unsigned short* lds, int t) {
    int row_in = t >> 3;                        // 0..31
    int kg = (t & 7) ^ (row_in & 7);            // pre-swizzled global slot
    const unsigned short* src = g + (size_t)row_in * ldK + kg * 8;
    unsigned short* dst = lds + ((t >> 6) << 9);  // wave-uniform base
#pragma unroll
    for (int c = 0; c < ROWS / 32; ++c) {
        __builtin_amdgcn_global_load_lds(
            (gas_t*)(unsigned long long)(src + (size_t)c * 32 * ldK),
            (las_t*)(unsigned)(unsigned long long)(dst + c * 2048),
            16, 0, 0);
    }
}

DI bf16x8 frag(const unsigned short* lds, int r, int kg) {
    return *(const bf16x8*)((const char*)lds + r * 128 + ((kg ^ (r & 7)) << 4));
}

// ------------- GEMM engine: C[M,N] = A[M,K] * B[N,K]^T, tile TM x 128 -------
// 16x16x32 MFMA (32x32 regressed: row&7 swizzle -> 4-way LDS conflict, r4 bench)
// MODE 0: QKV fused (TM=128): m0<512 -> qT C^T(+b0); <1024 -> kT(+b1); else vN nat(+b2)
// MODE 1: scores -> E = exp(acc*scale) bf16 C^T + partial row sums to spart
// MODE 2: PV -> bf16 C^T, scaled by 1/rowsum (from spart)
// MODE 3: proj -> f32 C^T + bias[ng] + residual
template <int TM, int MODE, int MINW>
__global__ __launch_bounds__(256, MINW) void gemm_bt(
        const unsigned short* __restrict__ A, const unsigned short* __restrict__ B,
        const float* __restrict__ b0, const float* __restrict__ b1,
        const float* __restrict__ b2,
        void* __restrict__ C0, void* __restrict__ C1, void* __restrict__ C2,
        const float* __restrict__ resid, float* __restrict__ spart,
        int M, int N, int K, float scale, size_t sA, size_t sB, size_t sC) {
    constexpr int MR = TM / 32;                       // per-wave m-fragments
    __shared__ __align__(16) unsigned short As[TM * 64];
    __shared__ __align__(16) unsigned short Bs[128 * 64];
    int bx = blockIdx.x;
    int b = bx & 7;                 // batch fastest -> XCD-resident per batch
    int tile = bx >> 3;
    int nTx = N >> 7;
    int tx = tile % nTx, ty = tile / nTx;
    int m0 = ty * TM, n0 = tx << 7;
    const unsigned short* Ag = A + sA * b + (size_t)m0 * K;
    const unsigned short* Bg = B + sB * b + (size_t)n0 * K;
    int t = threadIdx.x;
    int lane = t & 63, wid = t >> 6;
    int wm = (wid >> 1) * (TM / 2), wn = (wid & 1) * 64;
    const int l15 = lane & 15, lks = lane >> 4;

    f32x4 acc[MR][4];
#pragma unroll
    for (int i = 0; i < MR; ++i)
#pragma unroll
        for (int j = 0; j < 4; ++j) acc[i][j] = (f32x4){0.f, 0.f, 0.f, 0.f};

    for (int k0 = 0; k0 < K; k0 += 64) {
        stage_tile<TM>(Ag + k0, K, As, t);
        stage_tile<128>(Bg + k0, K, Bs, t);
        asm volatile("s_waitcnt vmcnt(0)" ::: "memory");
        __syncthreads();
#pragma unroll
        for (int kk = 0; kk < 2; ++kk) {
            bf16x8 a_[MR], b_[4];
#pragma unroll
            for (int m = 0; m < MR; ++m) a_[m] = frag(As, wm + m * 16 + l15, kk * 4 + lks);
#pragma unroll
            for (int n = 0; n < 4; ++n) b_[n] = frag(Bs, wn + n * 16 + l15, kk * 4 + lks);
#pragma unroll
            for (int m = 0; m < MR; ++m)
#pragma unroll
                for (int n = 0; n < 4; ++n)
                    acc[m][n] = __builtin_amdgcn_mfma_f32_16x16x32_bf16(a_[m], b_[n], acc[m][n], 0, 0, 0);
        }
        __syncthreads();
    }

    const int rbase = lks * 4;
    const size_t cb = sC * b;
    if constexpr (MODE == 0) {
        if (m0 < 1024) {
            unsigned short* Ct = (unsigned short*)(m0 < 512 ? C0 : C1) + cb;
            const float* bias = (m0 < 512) ? b0 : b1;
            int moff = (m0 < 512) ? 0 : 512;
#pragma unroll
            for (int m = 0; m < MR; ++m) {
                int mg = m0 - moff + wm + m * 16 + rbase;
                float bv4[4];
#pragma unroll
                for (int j = 0; j < 4; ++j) bv4[j] = bias[mg + j];
#pragma unroll
                for (int n = 0; n < 4; ++n) {
                    int ng = n0 + wn + n * 16 + l15;
                    f32x4 v = acc[m][n];
                    ushort4 o;
                    o.x = f2bf(v[0] + bv4[0]); o.y = f2bf(v[1] + bv4[1]);
                    o.z = f2bf(v[2] + bv4[2]); o.w = f2bf(v[3] + bv4[3]);
                    *(ushort4*)&Ct[(size_t)ng * 512 + mg] = o;
                }
            }
        } else {
            unsigned short* Vb = (unsigned short*)C2 + cb;
#pragma unroll
            for (int m = 0; m < MR; ++m) {
                int mg = m0 - 1024 + wm + m * 16 + rbase;
                float bv4[4];
#pragma unroll
                for (int j = 0; j < 4; ++j) bv4[j] = b2[mg + j];
#pragma unroll
                for (int n = 0; n < 4; ++n) {
                    int ng = n0 + wn + n * 16 + l15;
                    f32x4 v = acc[m][n];
#pragma unroll
                    for (int j = 0; j < 4; ++j)
                        Vb[(size_t)(mg + j) * 1024 + ng] = f2bf(v[j] + bv4[j]);
                }
            }
        }
    } else if constexpr (MODE == 1) {
        unsigned short* Ct = (unsigned short*)C0 + cb;
        float psum[4] = {0.f, 0.f, 0.f, 0.f};
#pragma unroll
        for (int m = 0; m < MR; ++m) {
            int mg = m0 + wm + m * 16 + rbase;
#pragma unroll
            for (int n = 0; n < 4; ++n) {
                int ng = n0 + wn + n * 16 + l15;
                f32x4 v = acc[m][n];
                float e0 = __expf(v[0] * scale), e1 = __expf(v[1] * scale);
                float e2 = __expf(v[2] * scale), e3 = __expf(v[3] * scale);
                psum[n] += (e0 + e1) + (e2 + e3);
                ushort4 o;
                o.x = f2bf(e0); o.y = f2bf(e1); o.z = f2bf(e2); o.w = f2bf(e3);
                *(ushort4*)&Ct[(size_t)ng * M + mg] = o;
            }
        }
        int rb = (m0 >> 7) * 2 + (wid >> 1);
#pragma unroll
        for (int n = 0; n < 4; ++n) {
            float p = psum[n];
            p += __shfl_xor(p, 16);
            p += __shfl_xor(p, 32);
            if (lks == 0) {
                int ng = n0 + wn + n * 16 + l15;
                spart[(size_t)(b * 16 + rb) * 1024 + ng] = p;
            }
        }
    } else if constexpr (MODE == 2) {
        unsigned short* Ct = (unsigned short*)C0 + cb;
        float inv[4];
#pragma unroll
        for (int n = 0; n < 4; ++n) {
            int ng = n0 + wn + n * 16 + l15;
            float ssum = 0.f;
#pragma unroll
            for (int k = 0; k < 16; ++k) ssum += spart[(size_t)(b * 16 + k) * 1024 + ng];
            inv[n] = 1.f / ssum;
        }
#pragma unroll
        for (int m = 0; m < MR; ++m) {
            int mg = m0 + wm + m * 16 + rbase;
#pragma unroll
            for (int n = 0; n < 4; ++n) {
                int ng = n0 + wn + n * 16 + l15;
                f32x4 v = acc[m][n];
                ushort4 o;
                o.x = f2bf(v[0] * inv[n]); o.y = f2bf(v[1] * inv[n]);
                o.z = f2bf(v[2] * inv[n]); o.w = f2bf(v[3] * inv[n]);
                *(ushort4*)&Ct[(size_t)ng * M + mg] = o;
            }
        }
    } else {
        float* Cf = (float*)C0 + cb;
#pragma unroll
        for (int m = 0; m < MR; ++m) {
            int mg = m0 + wm + m * 16 + rbase;
#pragma unroll
            for (int n = 0; n < 4; ++n) {
                int ng = n0 + wn + n * 16 + l15;
                float bn = b0[ng];
                f32x4 v = acc[m][n];
                const float* rp = resid + cb + (size_t)ng * M + mg;
                float4 o;
                o.x = v[0] + bn + rp[0]; o.y = v[1] + bn + rp[1];
                o.z = v[2] + bn + rp[2]; o.w = v[3] + bn + rp[3];
                *(float4*)&Cf[(size_t)ng * M + mg] = o;
            }
        }
    }
}

extern "C" void kernel_launch(void* const* d_in, const int* in_sizes, int n_in,
                              void* d_out, int out_size, void* d_ws, size_t ws_size,
                              hipStream_t stream) {
    const float* x  = (const float*)d_in[0];
    const float* gs = (const float*)d_in[1];
    const float* gb = (const float*)d_in[2];
    const float* wq = (const float*)d_in[3];
    const float* bq = (const float*)d_in[4];
    const float* wk = (const float*)d_in[5];
    const float* bk = (const float*)d_in[6];
    const float* wv = (const float*)d_in[7];
    const float* bv = (const float*)d_in[8];
    const float* wp = (const float*)d_in[9];
    const float* bp = (const float*)d_in[10];
    float* out = (float*)d_out;

    char* ws = (char*)d_ws;
    const size_t MB = 1u << 20;
    unsigned short* hT = (unsigned short*)(ws + 0);         // [b][1024][512]
    unsigned short* wb = (unsigned short*)(ws + 8 * MB);    // [wq;wk;wv;wp] bf16
    unsigned short* qT = (unsigned short*)(ws + 10 * MB);   // [b][1024][512]
    unsigned short* kT = (unsigned short*)(ws + 18 * MB);   // [b][1024][512]
    unsigned short* vN = (unsigned short*)(ws + 26 * MB);   // [b][512][1024]
    unsigned short* E  = (unsigned short*)(ws + 34 * MB);   // [b][1024][1024] bf16
    unsigned short* OT = (unsigned short*)(ws + 50 * MB);   // [b][1024][512]
    float2* gnpart     = (float2*)(ws + 58 * MB);           // 512 x float2
    float*  spart      = (float*)(ws + 58 * MB + 65536);    // [b][16][1024] f32

    const unsigned short* wpb = wb + 3 * 262144;
    const size_t sH = 1024 * 512;
    const size_t sS = 1024 * 1024;

    prep_kernel<<<1536, 256, 0, stream>>>(x, gnpart, wq, wk, wv, wp, wb);
    gn_applyT<<<512, 256, 0, stream>>>(x, gnpart, gs, gb, hT);

    // QKV fused: A = [Wq;Wk;Wv] (1536x512), B = hT -> qT, kT (C^T), vN (nat)
    gemm_bt<128, 0, 3><<<96 * 8, 256, 0, stream>>>(
        wb, hT, bq, bk, bv, qT, kT, vN, nullptr, nullptr,
        1536, 1024, 512, 1.f, 0, sH, sH);
    // scores: A=kT, B=qT -> E[i][j] = exp(s*scale) bf16 (C^T) + spart
    gemm_bt<128, 1, 3><<<64 * 8, 256, 0, stream>>>(
        kT, qT, nullptr, nullptr, nullptr, E, nullptr, nullptr, nullptr, spart,
        1024, 1024, 512, 0.044194173824159216f, sH, sH, sS);
    // PV: A=vN, B=E -> OT[i][c] (C^T), normalized by rowsum
    gemm_bt<64, 2, 3><<<64 * 8, 256, 0, stream>>>(
        vN, E, nullptr, nullptr, nullptr, OT, nullptr, nullptr, nullptr, spart,
        512, 1024, 1024, 1.f, sH, sS, sH);
    // proj: A=OT, B=Wp -> out[b][c][i] f32 (C^T) + bias[c] + residual
    gemm_bt<64, 3, 3><<<64 * 8, 256, 0, stream>>>(
        OT, wpb, bp, nullptr, nullptr, out, nullptr, nullptr, x, nullptr,
        1024, 512, 512, 1.f, sH, 0, (size_t)512 * 1024);
}

// Round 6
// 75.792 us; speedup vs baseline: 1.2002x; 1.0606x over previous
//
#include <hip/hip_runtime.h>
#include <hip/hip_bf16.h>

#define DI __device__ __forceinline__

typedef __bf16 bf16x8 __attribute__((ext_vector_type(8)));
typedef float f32x4 __attribute__((ext_vector_type(4)));

typedef const void __attribute__((address_space(1))) gas_t;
typedef void __attribute__((address_space(3))) las_t;

DI unsigned short f2bf(float f) {
    unsigned u = __builtin_bit_cast(unsigned, f);
    u += 0x7fffu + ((u >> 16) & 1u);   // RNE
    return (unsigned short)(u >> 16);
}

// ---------------- prep: GN stats (512 blocks) + weight cvt (1024 blocks) ----
// stats blocks: batch = bx&7 so x[b] warms XCD-b L2 (consumed by gn_applyT)
__global__ __launch_bounds__(256) void prep_kernel(const float* __restrict__ x,
                                                   float2* __restrict__ part,
                                                   const float* __restrict__ w0,
                                                   const float* __restrict__ w1,
                                                   const float* __restrict__ w2,
                                                   const float* __restrict__ w3,
                                                   unsigned short* __restrict__ wb) {
    int bx = blockIdx.x;
    int t = threadIdx.x;
    if (bx < 512) {
        // unit = (b,g,ch): 8 channels x 1024 px. batch in low 3 bits -> XCD
        int b = bx & 7, g = (bx >> 3) & 7, ch = bx >> 6;
        size_t base = ((size_t)b * 512 + g * 64 + ch * 8) * 1024;
        const float4* xp = (const float4*)(x + base);
        float s = 0.f, q = 0.f;
#pragma unroll
        for (int it = 0; it < 8; ++it) {
            float4 v = xp[it * 256 + t];
            s += (v.x + v.y) + (v.z + v.w);
            q += (v.x * v.x + v.y * v.y) + (v.z * v.z + v.w * v.w);
        }
#pragma unroll
        for (int o = 32; o; o >>= 1) { s += __shfl_xor(s, o); q += __shfl_xor(q, o); }
        __shared__ float rs[4], rq[4];
        int lane = t & 63, wid = t >> 6;
        if (!lane) { rs[wid] = s; rq[wid] = q; }
        __syncthreads();
        if (t == 0)
            part[((b * 8 + g) * 8) + ch] =
                make_float2(rs[0] + rs[1] + rs[2] + rs[3],
                            rq[0] + rq[1] + rq[2] + rq[3]);
    } else {
        int idx4 = bx - 512;                 // 0..1023
        int w = idx4 >> 8;
        const float* s = (w == 0) ? w0 : (w == 1) ? w1 : (w == 2) ? w2 : w3;
        unsigned short* o = wb + (size_t)w * 262144;
        int idx = (idx4 & 255) * 256 + t;
        float4 v = ((const float4*)s)[idx];
        ushort4 r;
        r.x = f2bf(v.x); r.y = f2bf(v.y); r.z = f2bf(v.z); r.w = f2bf(v.w);
        ((ushort4*)o)[idx] = r;
    }
}

// -------- GN apply + transposed write: x[b,c,hw] f32 -> hT[b,hw,c] bf16 -----
// batch = bx&7: reads x[b] from XCD-b L2 (warmed by prep), writes hT[b] into
// XCD-b L2 (consumed by QKV blocks with b = bx&7).
__global__ __launch_bounds__(256) void gn_applyT(const float* __restrict__ x,
                                                 const float2* __restrict__ part,
                                                 const float* __restrict__ gs,
                                                 const float* __restrict__ gb,
                                                 unsigned short* __restrict__ hT) {
    int bx = blockIdx.x;
    int b = bx & 7, g = (bx >> 3) & 7, ic = bx >> 6;
    int bg = b * 8 + g;
    float s = 0.f, q = 0.f;
#pragma unroll
    for (int k = 0; k < 8; ++k) { float2 p = part[bg * 8 + k]; s += p.x; q += p.y; }
    float mean = s * (1.f / 65536.f);
    float var = q * (1.f / 65536.f) - mean * mean;
    float rstd = rsqrtf(var + 1e-5f);

    __shared__ unsigned short tile[128 * 66];   // [i][c], stride 66
    int t = threadIdx.x;
    int i4 = t & 31, cq = t >> 5;
    size_t xbase = ((size_t)b * 512 + g * 64) * 1024 + ic * 128;
#pragma unroll
    for (int pass = 0; pass < 8; ++pass) {
        int c = pass * 8 + cq;
        float4 v = *(const float4*)&x[xbase + (size_t)c * 1024 + i4 * 4];
        int gc = g * 64 + c;
        float sc = gs[gc] * rstd, bi = gb[gc] - mean * sc;
        unsigned short* tp = &tile[(i4 * 4) * 66 + c];
        tp[0]   = f2bf(v.x * sc + bi);
        tp[66]  = f2bf(v.y * sc + bi);
        tp[132] = f2bf(v.z * sc + bi);
        tp[198] = f2bf(v.w * sc + bi);
    }
    __syncthreads();
    int i = t >> 1, h = t & 1;
    const unsigned short* tp2 = &tile[i * 66 + h * 32];
    unsigned short* op = &hT[(size_t)b * (1024 * 512) + (size_t)(ic * 128 + i) * 512 + g * 64 + h * 32];
#pragma unroll
    for (int cc = 0; cc < 4; ++cc) {
        unsigned short tmp[8];
#pragma unroll
        for (int j = 0; j < 8; ++j) tmp[j] = tp2[cc * 8 + j];
        *(uint4*)&op[cc * 8] = *(const uint4*)tmp;
    }
}

// ------- staging: global tile (ROWS x 64 k bf16) -> LDS via LDS-DMA ---------
// LDS: linear rows of 128B; slot s of row r holds global k-slot s^(r&7).
template <int ROWS>
DI void stage_tile(const unsigned short* __restrict__ g, int ldK,
                   unsigned short* lds, int t) {
    int row_in = t >> 3;                        // 0..31
    int kg = (t & 7) ^ (row_in & 7);            // pre-swizzled global slot
    const unsigned short* src = g + (size_t)row_in * ldK + kg * 8;
    unsigned short* dst = lds + ((t >> 6) << 9);  // wave-uniform base
#pragma unroll
    for (int c = 0; c < ROWS / 32; ++c) {
        __builtin_amdgcn_global_load_lds(
            (gas_t*)(unsigned long long)(src + (size_t)c * 32 * ldK),
            (las_t*)(unsigned)(unsigned long long)(dst + c * 2048),
            16, 0, 0);
    }
}

DI bf16x8 frag(const unsigned short* lds, int r, int kg) {
    return *(const bf16x8*)((const char*)lds + r * 128 + ((kg ^ (r & 7)) << 4));
}

template <int MR>
DI void compute_step(const unsigned short* As_, const unsigned short* Bs_,
                     f32x4 (&acc)[MR][4], int wm, int wn, int l15, int lks) {
#pragma unroll
    for (int kk = 0; kk < 2; ++kk) {
        bf16x8 a_[MR], b_[4];
#pragma unroll
        for (int m = 0; m < MR; ++m) a_[m] = frag(As_, wm + m * 16 + l15, kk * 4 + lks);
#pragma unroll
        for (int n = 0; n < 4; ++n) b_[n] = frag(Bs_, wn + n * 16 + l15, kk * 4 + lks);
#pragma unroll
        for (int m = 0; m < MR; ++m)
#pragma unroll
            for (int n = 0; n < 4; ++n)
                acc[m][n] = __builtin_amdgcn_mfma_f32_16x16x32_bf16(a_[m], b_[n], acc[m][n], 0, 0, 0);
    }
}

// ------------- GEMM engine: C[M,N] = A[M,K] * B[N,K]^T, tile TM x 128 -------
// 16x16x32 MFMA (32x32 regressed: row&7 swizzle -> 4-way LDS conflict, r4 bench)
// PIPE=0: 1-phase (stage, drain, compute). PIPE=1: 2-phase double-buffer,
// T3-minimum recipe: STAGE(next) issued BEFORE compute, vmcnt(0)+barrier after.
// MODE 0: QKV fused (TM=128): m0<512 -> qT C^T(+b0); <1024 -> kT(+b1); else vN nat(+b2)
// MODE 1: scores -> E = exp(acc*scale) bf16 C^T + partial row sums to spart
// MODE 2: PV -> bf16 C^T, scaled by 1/rowsum (from spart)
// MODE 3: proj -> f32 C^T + bias[ng] + residual
template <int TM, int MODE, int MINW, int PIPE>
__global__ __launch_bounds__(256, MINW) void gemm_bt(
        const unsigned short* __restrict__ A, const unsigned short* __restrict__ B,
        const float* __restrict__ b0, const float* __restrict__ b1,
        const float* __restrict__ b2,
        void* __restrict__ C0, void* __restrict__ C1, void* __restrict__ C2,
        const float* __restrict__ resid, float* __restrict__ spart,
        int M, int N, int K, float scale, size_t sA, size_t sB, size_t sC) {
    constexpr int MR = TM / 32;                       // per-wave m-fragments
    constexpr int NBUF = PIPE ? 2 : 1;
    __shared__ __align__(16) unsigned short As[NBUF][TM * 64];
    __shared__ __align__(16) unsigned short Bs[NBUF][128 * 64];
    int bx = blockIdx.x;
    int b = bx & 7;                 // batch fastest -> XCD-resident per batch
    int tile = bx >> 3;
    int nTx = N >> 7;
    int tx = tile % nTx, ty = tile / nTx;
    int m0 = ty * TM, n0 = tx << 7;
    const unsigned short* Ag = A + sA * b + (size_t)m0 * K;
    const unsigned short* Bg = B + sB * b + (size_t)n0 * K;
    int t = threadIdx.x;
    int lane = t & 63, wid = t >> 6;
    int wm = (wid >> 1) * (TM / 2), wn = (wid & 1) * 64;
    const int l15 = lane & 15, lks = lane >> 4;

    f32x4 acc[MR][4];
#pragma unroll
    for (int i = 0; i < MR; ++i)
#pragma unroll
        for (int j = 0; j < 4; ++j) acc[i][j] = (f32x4){0.f, 0.f, 0.f, 0.f};

    // hoisted epilogue operands: latency hides under the staging prologue
    float inv[4];
    if constexpr (MODE == 2) {
#pragma unroll
        for (int n = 0; n < 4; ++n) {
            int ng = n0 + wn + n * 16 + l15;
            float ssum = 0.f;
#pragma unroll
            for (int k = 0; k < 16; ++k) ssum += spart[(size_t)(b * 16 + k) * 1024 + ng];
            inv[n] = 1.f / ssum;
        }
    }
    float bn4[4];
    if constexpr (MODE == 3) {
#pragma unroll
        for (int n = 0; n < 4; ++n) bn4[n] = b0[n0 + wn + n * 16 + l15];
    }

    if constexpr (PIPE == 0) {
        for (int k0 = 0; k0 < K; k0 += 64) {
            stage_tile<TM>(Ag + k0, K, &As[0][0], t);
            stage_tile<128>(Bg + k0, K, &Bs[0][0], t);
            asm volatile("s_waitcnt vmcnt(0)" ::: "memory");
            __syncthreads();
            compute_step<MR>(&As[0][0], &Bs[0][0], acc, wm, wn, l15, lks);
            __syncthreads();
        }
    } else {
        stage_tile<TM>(Ag, K, &As[0][0], t);
        stage_tile<128>(Bg, K, &Bs[0][0], t);
        asm volatile("s_waitcnt vmcnt(0)" ::: "memory");
        __syncthreads();
        int cur = 0;
        for (int k0 = 0; k0 < K; k0 += 64) {
            if (k0 + 64 < K) {
                stage_tile<TM>(Ag + k0 + 64, K, &As[cur ^ 1][0], t);
                stage_tile<128>(Bg + k0 + 64, K, &Bs[cur ^ 1][0], t);
            }
            compute_step<MR>(&As[cur][0], &Bs[cur][0], acc, wm, wn, l15, lks);
            if (k0 + 64 < K) {
                asm volatile("s_waitcnt vmcnt(0)" ::: "memory");
                __syncthreads();
            }
            cur ^= 1;
        }
    }

    const int rbase = lks * 4;
    const size_t cb = sC * b;
    if constexpr (MODE == 0) {
        if (m0 < 1024) {
            unsigned short* Ct = (unsigned short*)(m0 < 512 ? C0 : C1) + cb;
            const float* bias = (m0 < 512) ? b0 : b1;
            int moff = (m0 < 512) ? 0 : 512;
#pragma unroll
            for (int m = 0; m < MR; ++m) {
                int mg = m0 - moff + wm + m * 16 + rbase;
                float bv4[4];
#pragma unroll
                for (int j = 0; j < 4; ++j) bv4[j] = bias[mg + j];
#pragma unroll
                for (int n = 0; n < 4; ++n) {
                    int ng = n0 + wn + n * 16 + l15;
                    f32x4 v = acc[m][n];
                    ushort4 o;
                    o.x = f2bf(v[0] + bv4[0]); o.y = f2bf(v[1] + bv4[1]);
                    o.z = f2bf(v[2] + bv4[2]); o.w = f2bf(v[3] + bv4[3]);
                    *(ushort4*)&Ct[(size_t)ng * 512 + mg] = o;
                }
            }
        } else {
            unsigned short* Vb = (unsigned short*)C2 + cb;
#pragma unroll
            for (int m = 0; m < MR; ++m) {
                int mg = m0 - 1024 + wm + m * 16 + rbase;
                float bv4[4];
#pragma unroll
                for (int j = 0; j < 4; ++j) bv4[j] = b2[mg + j];
#pragma unroll
                for (int n = 0; n < 4; ++n) {
                    int ng = n0 + wn + n * 16 + l15;
                    f32x4 v = acc[m][n];
#pragma unroll
                    for (int j = 0; j < 4; ++j)
                        Vb[(size_t)(mg + j) * 1024 + ng] = f2bf(v[j] + bv4[j]);
                }
            }
        }
    } else if constexpr (MODE == 1) {
        unsigned short* Ct = (unsigned short*)C0 + cb;
        float psum[4] = {0.f, 0.f, 0.f, 0.f};
#pragma unroll
        for (int m = 0; m < MR; ++m) {
            int mg = m0 + wm + m * 16 + rbase;
#pragma unroll
            for (int n = 0; n < 4; ++n) {
                int ng = n0 + wn + n * 16 + l15;
                f32x4 v = acc[m][n];
                float e0 = __expf(v[0] * scale), e1 = __expf(v[1] * scale);
                float e2 = __expf(v[2] * scale), e3 = __expf(v[3] * scale);
                psum[n] += (e0 + e1) + (e2 + e3);
                ushort4 o;
                o.x = f2bf(e0); o.y = f2bf(e1); o.z = f2bf(e2); o.w = f2bf(e3);
                *(ushort4*)&Ct[(size_t)ng * M + mg] = o;
            }
        }
        int rb = (m0 >> 7) * 2 + (wid >> 1);
#pragma unroll
        for (int n = 0; n < 4; ++n) {
            float p = psum[n];
            p += __shfl_xor(p, 16);
            p += __shfl_xor(p, 32);
            if (lks == 0) {
                int ng = n0 + wn + n * 16 + l15;
                spart[(size_t)(b * 16 + rb) * 1024 + ng] = p;
            }
        }
    } else if constexpr (MODE == 2) {
        unsigned short* Ct = (unsigned short*)C0 + cb;
#pragma unroll
        for (int m = 0; m < MR; ++m) {
            int mg = m0 + wm + m * 16 + rbase;
#pragma unroll
            for (int n = 0; n < 4; ++n) {
                int ng = n0 + wn + n * 16 + l15;
                f32x4 v = acc[m][n];
                ushort4 o;
                o.x = f2bf(v[0] * inv[n]); o.y = f2bf(v[1] * inv[n]);
                o.z = f2bf(v[2] * inv[n]); o.w = f2bf(v[3] * inv[n]);
                *(ushort4*)&Ct[(size_t)ng * M + mg] = o;
            }
        }
    } else {
        float* Cf = (float*)C0 + cb;
#pragma unroll
        for (int m = 0; m < MR; ++m) {
            int mg = m0 + wm + m * 16 + rbase;
#pragma unroll
            for (int n = 0; n < 4; ++n) {
                int ng = n0 + wn + n * 16 + l15;
                f32x4 v = acc[m][n];
                const float* rp = resid + cb + (size_t)ng * M + mg;
                float4 o;
                o.x = v[0] + bn4[n] + rp[0]; o.y = v[1] + bn4[n] + rp[1];
                o.z = v[2] + bn4[n] + rp[2]; o.w = v[3] + bn4[n] + rp[3];
                *(float4*)&Cf[(size_t)ng * M + mg] = o;
            }
        }
    }
}

extern "C" void kernel_launch(void* const* d_in, const int* in_sizes, int n_in,
                              void* d_out, int out_size, void* d_ws, size_t ws_size,
                              hipStream_t stream) {
    const float* x  = (const float*)d_in[0];
    const float* gs = (const float*)d_in[1];
    const float* gb = (const float*)d_in[2];
    const float* wq = (const float*)d_in[3];
    const float* bq = (const float*)d_in[4];
    const float* wk = (const float*)d_in[5];
    const float* bk = (const float*)d_in[6];
    const float* wv = (const float*)d_in[7];
    const float* bv = (const float*)d_in[8];
    const float* wp = (const float*)d_in[9];
    const float* bp = (const float*)d_in[10];
    float* out = (float*)d_out;

    char* ws = (char*)d_ws;
    const size_t MB = 1u << 20;
    unsigned short* hT = (unsigned short*)(ws + 0);         // [b][1024][512]
    unsigned short* wb = (unsigned short*)(ws + 8 * MB);    // [wq;wk;wv;wp] bf16
    unsigned short* qT = (unsigned short*)(ws + 10 * MB);   // [b][1024][512]
    unsigned short* kT = (unsigned short*)(ws + 18 * MB);   // [b][1024][512]
    unsigned short* vN = (unsigned short*)(ws + 26 * MB);   // [b][512][1024]
    unsigned short* E  = (unsigned short*)(ws + 34 * MB);   // [b][1024][1024] bf16
    unsigned short* OT = (unsigned short*)(ws + 50 * MB);   // [b][1024][512]
    float2* gnpart     = (float2*)(ws + 58 * MB);           // 512 x float2
    float*  spart      = (float*)(ws + 58 * MB + 65536);    // [b][16][1024] f32

    const unsigned short* wpb = wb + 3 * 262144;
    const size_t sH = 1024 * 512;
    const size_t sS = 1024 * 1024;

    prep_kernel<<<1536, 256, 0, stream>>>(x, gnpart, wq, wk, wv, wp, wb);
    gn_applyT<<<512, 256, 0, stream>>>(x, gnpart, gs, gb, hT);

    // QKV fused: A = [Wq;Wk;Wv] (1536x512), B = hT -> qT, kT (C^T), vN (nat)
    // 768 blocks = exactly 3/CU single-buffered: keep 1-phase.
    gemm_bt<128, 0, 3, 0><<<96 * 8, 256, 0, stream>>>(
        wb, hT, bq, bk, bv, qT, kT, vN, nullptr, nullptr,
        1536, 1024, 512, 1.f, 0, sH, sH);
    // scores: A=kT, B=qT -> E[i][j] = exp(s*scale) bf16 (C^T) + spart
    // 512 blocks = exactly 2/CU with 64KB dbuf LDS: 2-phase pipeline.
    gemm_bt<128, 1, 2, 1><<<64 * 8, 256, 0, stream>>>(
        kT, qT, nullptr, nullptr, nullptr, E, nullptr, nullptr, nullptr, spart,
        1024, 1024, 512, 0.044194173824159216f, sH, sH, sS);
    // PV: A=vN, B=E -> OT[i][c] (C^T), normalized by rowsum; 2-phase
    gemm_bt<64, 2, 2, 1><<<64 * 8, 256, 0, stream>>>(
        vN, E, nullptr, nullptr, nullptr, OT, nullptr, nullptr, nullptr, spart,
        512, 1024, 1024, 1.f, sH, sS, sH);
    // proj: A=OT, B=Wp -> out[b][c][i] f32 (C^T) + bias[c] + residual; 2-phase
    gemm_bt<64, 3, 2, 1><<<64 * 8, 256, 0, stream>>>(
        OT, wpb, bp, nullptr, nullptr, out, nullptr, nullptr, x, nullptr,
        1024, 512, 512, 1.f, sH, 0, (size_t)512 * 1024);
}